// Round 1
// baseline (5937.284 us; speedup 1.0000x reference)
//
#include <hip/hip_runtime.h>

typedef _Float16 f16;
typedef _Float16 f16x8 __attribute__((ext_vector_type(8)));
typedef _Float16 f16x4 __attribute__((ext_vector_type(4)));
typedef float    f32x4 __attribute__((ext_vector_type(4)));

static constexpr int Bb  = 32;
static constexpr int Tt  = 128;
static constexpr int HID = 1024;
static constexpr int ZD  = 256;
static constexpr int DE  = 512;
static constexpr int VOC = 32000;
static constexpr int BT  = Bb * Tt;   // 4096
static constexpr int G4  = 4 * HID;   // 4096

// ---- async global->LDS, 16B per lane; LDS dest = wave-uniform base + lane*16 ----
__device__ __forceinline__ void gld_lds16(const void* g, void* l) {
  __builtin_amdgcn_global_load_lds((const __attribute__((address_space(1))) unsigned int*)g,
                                   (__attribute__((address_space(3))) unsigned int*)l,
                                   16, 0, 0);
}

// ---------------- f32 -> f16 convert (vectorized) ----------------
__global__ void cvt_kernel(const float* __restrict__ s, f16* __restrict__ d, int n4) {
  int i = blockIdx.x * blockDim.x + threadIdx.x;
  int st = gridDim.x * blockDim.x;
  for (; i < n4; i += st) {
    float4 v = ((const float4*)s)[i];
    f16x4 o = { (f16)v.x, (f16)v.y, (f16)v.z, (f16)v.w };
    ((f16x4*)d)[i] = o;
  }
}

// ---------------- embedding gather -> f16 ----------------
__global__ void gather_kernel(const float* __restrict__ emb, const int* __restrict__ x,
                              f16* __restrict__ E) {
  int g = blockIdx.x * 256 + threadIdx.x;   // BT*DE/8 threads
  int m = g >> 6, seg = (g & 63) * 8;
  int idx = x[m];
  const float* src = emb + (size_t)idx * DE + seg;
  float4 a = *(const float4*)src;
  float4 b = *(const float4*)(src + 4);
  f16x8 o = { (f16)a.x,(f16)a.y,(f16)a.z,(f16)a.w,(f16)b.x,(f16)b.y,(f16)b.z,(f16)b.w };
  *(f16x8*)(E + (size_t)m * DE + seg) = o;
}

// ---------------- bias sum ----------------
__global__ void bsum_kernel(const float* __restrict__ a, const float* __restrict__ b,
                            float* __restrict__ o, int n) {
  int i = blockIdx.x * blockDim.x + threadIdx.x;
  if (i < n) o[i] = a[i] + b[i];
}

// ---------------- h0 = tanh(z @ W_h^T + b_h), store f16 ----------------
__global__ __launch_bounds__(256) void h0_kernel(const float* __restrict__ z,
                                                 const float* __restrict__ W_h,
                                                 const float* __restrict__ b_h,
                                                 f16* __restrict__ h0f) {
  __shared__ float zs[32][260];  // +4 pad vs bank conflicts
  __shared__ float wsl[8][260];
  const int jc = blockIdx.x, tid = threadIdx.x;
  #pragma unroll
  for (int it = 0; it < 8; ++it) {          // 2048 float4 of z
    int idx = it * 256 + tid;
    float4 v = ((const float4*)z)[idx];
    int b = idx >> 6, k = (idx & 63) * 4;
    zs[b][k] = v.x; zs[b][k+1] = v.y; zs[b][k+2] = v.z; zs[b][k+3] = v.w;
  }
  #pragma unroll
  for (int it = 0; it < 2; ++it) {          // 512 float4 of W_h rows jc*8..+8
    int idx = it * 256 + tid;
    float4 v = ((const float4*)(W_h + (size_t)jc * 8 * ZD))[idx];
    int r = idx >> 6, k = (idx & 63) * 4;
    wsl[r][k] = v.x; wsl[r][k+1] = v.y; wsl[r][k+2] = v.z; wsl[r][k+3] = v.w;
  }
  __syncthreads();
  const int b = tid >> 3, jj = tid & 7;
  const int j = jc * 8 + jj;
  float acc = b_h[j];
  for (int k = 0; k < ZD; ++k) acc += zs[b][k] * wsl[jj][k];
  h0f[(size_t)b * HID + j] = (f16)tanhf(acc);
}

// ---------------- GEMM: C[M,N] = A[M,K] @ B[N,K]^T + bias[N]  (f16 in, f32 out) ----
// m97 structure: 128x128 tile, BK=64, 4 waves (2x2), 16x16x32 f16 MFMA.
__global__ __launch_bounds__(256, 2) void gemm_kernel(
    const f16* __restrict__ A, const f16* __restrict__ B,
    const float* __restrict__ bias, float* __restrict__ C,
    int M, int N, int K) {
  __shared__ f16 As[128 * 64];
  __shared__ f16 Bs[128 * 64];
  const int n0 = blockIdx.x * 128, m0 = blockIdx.y * 128;
  const int tid = threadIdx.x, wid = tid >> 6, lane = tid & 63;
  const int wm = wid >> 1, wn = wid & 1;
  const int sr = lane >> 3, sk = (lane & 7) * 8;   // staging: 8 rows x 128B per issue
  f32x4 acc[4][4] = {};
  for (int k0 = 0; k0 < K; k0 += 64) {
    __syncthreads();
    #pragma unroll
    for (int i = 0; i < 4; ++i) {
      int rr = (wid * 4 + i) * 8;
      gld_lds16(A + (size_t)(m0 + rr + sr) * K + k0 + sk, &As[rr * 64]);
      gld_lds16(B + (size_t)(n0 + rr + sr) * K + k0 + sk, &Bs[rr * 64]);
    }
    __syncthreads();
    #pragma unroll
    for (int ks = 0; ks < 2; ++ks) {
      f16x8 af[4], bf[4];
      #pragma unroll
      for (int mt = 0; mt < 4; ++mt)
        af[mt] = *(const f16x8*)&As[(wm * 64 + mt * 16 + (lane & 15)) * 64 + ks * 32 + (lane >> 4) * 8];
      #pragma unroll
      for (int nt = 0; nt < 4; ++nt)
        bf[nt] = *(const f16x8*)&Bs[(wn * 64 + nt * 16 + (lane & 15)) * 64 + ks * 32 + (lane >> 4) * 8];
      #pragma unroll
      for (int mt = 0; mt < 4; ++mt)
        #pragma unroll
        for (int nt = 0; nt < 4; ++nt)
          acc[mt][nt] = __builtin_amdgcn_mfma_f32_16x16x32_f16(af[mt], bf[nt], acc[mt][nt], 0, 0, 0);
    }
  }
  #pragma unroll
  for (int nt = 0; nt < 4; ++nt) {
    int col = n0 + wn * 64 + nt * 16 + (lane & 15);
    float bv = bias[col];
    #pragma unroll
    for (int mt = 0; mt < 4; ++mt) {
      int row = m0 + wm * 64 + mt * 16 + (lane >> 4) * 4;
      #pragma unroll
      for (int p = 0; p < 4; ++p)
        C[(size_t)(row + p) * N + col] = acc[mt][nt][p] + bv;
    }
  }
}

// ---------------- persistent LSTM recurrence ----------------
// 256 blocks x 256 threads; block bid owns hidden units j0=bid*4..+4 (16 W_hh rows in LDS).
// Per step: stage h_{t-1} (f16) to LDS -> MFMA (16 gate-rows x 32 batches, K=1024 split
// over 4 waves) -> LDS reduce -> LSTM update (c in regs) -> write h_t -> grid barrier.
__global__ __launch_bounds__(256, 1) void lstm_kernel(
    const f16* __restrict__ Whh16,   // [4096][1024]
    const float* __restrict__ XG,    // [BT][4096] rows = b*T+t
    const f16* __restrict__ h0f,     // [32][1024]
    f16* __restrict__ HS,            // [BT][1024] rows = b*T+t
    unsigned int* __restrict__ bar) {
  const int bid = blockIdx.x;
  const int tid = threadIdx.x, lane = tid & 63, wid = tid >> 6;
  __shared__ f16 Wl[16][1032];      // +8 f16 pad: frag reads ~2-way banked
  __shared__ f16 hl[32][1032];
  __shared__ float part[4][256];
  // load W_hh slice: row i=q*4+u  <- global row q*1024 + bid*4 + u
  #pragma unroll
  for (int it = 0; it < 8; ++it) {
    int cc = it * 256 + tid;                 // 2048 chunks of 8 f16
    int i = cc >> 7, ko = (cc & 127) * 8;
    int grow = (i >> 2) * HID + bid * 4 + (i & 3);
    *(f16x8*)&Wl[i][ko] = *(const f16x8*)(Whh16 + (size_t)grow * HID + ko);
  }
  float creg = 0.f;                          // c-state: threads 0..127 hold (b,u)
  for (int t = 0; t < Tt; ++t) {
    // stage h_{t-1}
    {
      int b = tid >> 3, seg = tid & 7;
      const f16* hb = (t == 0) ? (h0f + (size_t)b * HID)
                               : (HS + (size_t)(b * Tt + t - 1) * HID);
      #pragma unroll
      for (int it = 0; it < 16; ++it) {
        int ko = seg * 128 + it * 8;
        *(f16x8*)&hl[b][ko] = *(const f16x8*)(hb + ko);
      }
    }
    __syncthreads();
    // gate GEMM: C[16 rows][32 batches]; wave = (batch-half, K-half)
    {
      const int nh = wid & 1, kh = wid >> 1;
      f32x4 acc = {0.f, 0.f, 0.f, 0.f};
      #pragma unroll
      for (int kk = 0; kk < 16; ++kk) {
        int k0 = kh * 512 + kk * 32 + (lane >> 4) * 8;
        f16x8 af = *(const f16x8*)&Wl[lane & 15][k0];
        f16x8 bf = *(const f16x8*)&hl[nh * 16 + (lane & 15)][k0];
        acc = __builtin_amdgcn_mfma_f32_16x16x32_f16(af, bf, acc, 0, 0, 0);
      }
      #pragma unroll
      for (int p = 0; p < 4; ++p)
        part[wid][((lane >> 4) * 4 + p) * 16 + (lane & 15)] = acc[p];
    }
    __syncthreads();
    // LSTM update for (b,u), threads 0..127
    if (tid < 128) {
      int b = tid >> 2, u = tid & 3;
      int nh = b >> 4, bl = b & 15;
      size_t xrow = (size_t)(b * Tt + t) * G4;
      float g4[4];
      #pragma unroll
      for (int q = 0; q < 4; ++q)
        g4[q] = part[nh][(q * 4 + u) * 16 + bl] + part[2 + nh][(q * 4 + u) * 16 + bl]
              + XG[xrow + q * HID + bid * 4 + u];
      float ig = 1.f / (1.f + __expf(-g4[0]));
      float fg = 1.f / (1.f + __expf(-g4[1]));
      float gg = tanhf(g4[2]);
      float og = 1.f / (1.f + __expf(-g4[3]));
      creg = fg * creg + ig * gg;
      float h = og * tanhf(creg);
      HS[(size_t)(b * Tt + t) * HID + bid * 4 + u] = (f16)h;
    }
    if (t != Tt - 1) {
      __threadfence();      // per-wave release: drain stores + L2 writeback
      __syncthreads();
      if (tid == 0) {
        __hip_atomic_fetch_add(bar, 1u, __ATOMIC_ACQ_REL, __HIP_MEMORY_SCOPE_AGENT);
        unsigned tgt = 256u * (unsigned)(t + 1);
        while (__hip_atomic_load(bar, __ATOMIC_ACQUIRE, __HIP_MEMORY_SCOPE_AGENT) < tgt) { }
      }
      __syncthreads();
    }
  }
}

extern "C" void kernel_launch(void* const* d_in, const int* in_sizes, int n_in,
                              void* d_out, int out_size, void* d_ws, size_t ws_size,
                              hipStream_t stream) {
  const float* z     = (const float*)d_in[0];
  const int*   x     = (const int*)d_in[1];
  const float* W_h   = (const float*)d_in[2];
  const float* b_h   = (const float*)d_in[3];
  const float* emb   = (const float*)d_in[4];
  const float* W_ih  = (const float*)d_in[5];
  const float* W_hh  = (const float*)d_in[6];
  const float* b_ih  = (const float*)d_in[7];
  const float* b_hh  = (const float*)d_in[8];
  const float* W_out = (const float*)d_in[9];
  const float* b_out = (const float*)d_in[10];
  float* out = (float*)d_out;

  char* ws = (char*)d_ws;
  size_t off = 0;
  auto carve = [&](size_t n) { char* p = ws + off; off += (n + 255) & ~(size_t)255; return p; };
  f16*   E16    = (f16*)carve((size_t)BT * DE * 2);     // 4 MB
  f16*   Wih16  = (f16*)carve((size_t)G4 * DE * 2);     // 4 MB
  f16*   Whh16  = (f16*)carve((size_t)G4 * HID * 2);    // 8 MB
  f16*   Wout16 = (f16*)carve((size_t)VOC * HID * 2);   // 64 MB
  float* XG     = (float*)carve((size_t)BT * G4 * 4);   // 64 MB
  f16*   HS     = (f16*)carve((size_t)BT * HID * 2);    // 8 MB
  f16*   h0f    = (f16*)carve((size_t)Bb * HID * 2);
  float* bs     = (float*)carve((size_t)G4 * 4);
  unsigned* bar = (unsigned*)carve(256);

  hipMemsetAsync(bar, 0, 256, stream);   // reset grid barrier each call (graph-safe)

  cvt_kernel<<<2048, 256, 0, stream>>>(W_ih,  Wih16,  G4 * DE / 4);
  cvt_kernel<<<2048, 256, 0, stream>>>(W_hh,  Whh16,  G4 * HID / 4);
  cvt_kernel<<<2048, 256, 0, stream>>>(W_out, Wout16, VOC * HID / 4);
  gather_kernel<<<BT * DE / 8 / 256, 256, 0, stream>>>(emb, x, E16);
  bsum_kernel<<<16, 256, 0, stream>>>(b_ih, b_hh, bs, G4);
  h0_kernel<<<128, 256, 0, stream>>>(z, W_h, b_h, h0f);

  dim3 g1(G4 / 128, BT / 128);     // 32 x 32
  gemm_kernel<<<g1, 256, 0, stream>>>(E16, Wih16, bs, XG, BT, G4, DE);

  lstm_kernel<<<256, 256, 0, stream>>>(Whh16, XG, h0f, HS, bar);

  dim3 g2(VOC / 128, BT / 128);    // 250 x 32
  gemm_kernel<<<g2, 256, 0, stream>>>(HS, Wout16, b_out, out, BT, VOC, HID);
}

// Round 2
// 3607.544 us; speedup vs baseline: 1.6458x; 1.6458x over previous
//
#include <hip/hip_runtime.h>

typedef _Float16 f16;
typedef _Float16 f16x8 __attribute__((ext_vector_type(8)));
typedef _Float16 f16x4 __attribute__((ext_vector_type(4)));
typedef float    f32x4 __attribute__((ext_vector_type(4)));

static constexpr int Bb  = 32;
static constexpr int Tt  = 128;
static constexpr int HID = 1024;
static constexpr int ZD  = 256;
static constexpr int DE  = 512;
static constexpr int VOC = 32000;
static constexpr int BT  = Bb * Tt;   // 4096
static constexpr int G4  = 4 * HID;   // 4096
static constexpr int NB  = 128;       // lstm blocks (8 hidden units each)

// ---- async global->LDS, 16B per lane; LDS dest = wave-uniform base + lane*16 ----
__device__ __forceinline__ void gld_lds16(const void* g, void* l) {
  __builtin_amdgcn_global_load_lds((const __attribute__((address_space(1))) unsigned int*)g,
                                   (__attribute__((address_space(3))) unsigned int*)l,
                                   16, 0, 0);
}

// ---------------- f32 -> f16 convert (vectorized) ----------------
__global__ void cvt_kernel(const float* __restrict__ s, f16* __restrict__ d, int n4) {
  int i = blockIdx.x * blockDim.x + threadIdx.x;
  int st = gridDim.x * blockDim.x;
  for (; i < n4; i += st) {
    float4 v = ((const float4*)s)[i];
    f16x4 o = { (f16)v.x, (f16)v.y, (f16)v.z, (f16)v.w };
    ((f16x4*)d)[i] = o;
  }
}

// ---------------- embedding gather -> f16 ----------------
__global__ void gather_kernel(const float* __restrict__ emb, const int* __restrict__ x,
                              f16* __restrict__ E) {
  int g = blockIdx.x * 256 + threadIdx.x;   // BT*DE/8 threads
  int m = g >> 6, seg = (g & 63) * 8;
  int idx = x[m];
  const float* src = emb + (size_t)idx * DE + seg;
  float4 a = *(const float4*)src;
  float4 b = *(const float4*)(src + 4);
  f16x8 o = { (f16)a.x,(f16)a.y,(f16)a.z,(f16)a.w,(f16)b.x,(f16)b.y,(f16)b.z,(f16)b.w };
  *(f16x8*)(E + (size_t)m * DE + seg) = o;
}

// ---------------- bias sum ----------------
__global__ void bsum_kernel(const float* __restrict__ a, const float* __restrict__ b,
                            float* __restrict__ o, int n) {
  int i = blockIdx.x * blockDim.x + threadIdx.x;
  if (i < n) o[i] = a[i] + b[i];
}

// ---------------- h0 = tanh(z @ W_h^T + b_h), store f16 ----------------
__global__ __launch_bounds__(256) void h0_kernel(const float* __restrict__ z,
                                                 const float* __restrict__ W_h,
                                                 const float* __restrict__ b_h,
                                                 f16* __restrict__ h0f) {
  __shared__ float zs[32][260];
  __shared__ float wsl[8][260];
  const int jc = blockIdx.x, tid = threadIdx.x;
  #pragma unroll
  for (int it = 0; it < 8; ++it) {
    int idx = it * 256 + tid;
    float4 v = ((const float4*)z)[idx];
    int b = idx >> 6, k = (idx & 63) * 4;
    zs[b][k] = v.x; zs[b][k+1] = v.y; zs[b][k+2] = v.z; zs[b][k+3] = v.w;
  }
  #pragma unroll
  for (int it = 0; it < 2; ++it) {
    int idx = it * 256 + tid;
    float4 v = ((const float4*)(W_h + (size_t)jc * 8 * ZD))[idx];
    int r = idx >> 6, k = (idx & 63) * 4;
    wsl[r][k] = v.x; wsl[r][k+1] = v.y; wsl[r][k+2] = v.z; wsl[r][k+3] = v.w;
  }
  __syncthreads();
  const int b = tid >> 3, jj = tid & 7;
  const int j = jc * 8 + jj;
  float acc = b_h[j];
  for (int k = 0; k < ZD; ++k) acc += zs[b][k] * wsl[jj][k];
  h0f[(size_t)b * HID + j] = (f16)tanhf(acc);
}

// ---------------- GEMM: C = A[M,K] @ B[N,K]^T + bias[N]  (f16 in, f32 out) --------
// XGOUT=false: C[row][col] standard.  XGOUT=true: C laid out [g][b][t] float,
// i.e. store at ((col*32 + b)*128 + t) with row = b*128 + t (float4 over t).
template <bool XGOUT>
__global__ __launch_bounds__(256, 2) void gemm_kernel(
    const f16* __restrict__ A, const f16* __restrict__ B,
    const float* __restrict__ bias, float* __restrict__ C,
    int M, int N, int K) {
  __shared__ f16 As[128 * 64];
  __shared__ f16 Bs[128 * 64];
  const int n0 = blockIdx.x * 128, m0 = blockIdx.y * 128;
  const int tid = threadIdx.x, wid = tid >> 6, lane = tid & 63;
  const int wm = wid >> 1, wn = wid & 1;
  const int sr = lane >> 3, sk = (lane & 7) * 8;
  f32x4 acc[4][4] = {};
  for (int k0 = 0; k0 < K; k0 += 64) {
    __syncthreads();
    #pragma unroll
    for (int i = 0; i < 4; ++i) {
      int rr = (wid * 4 + i) * 8;
      gld_lds16(A + (size_t)(m0 + rr + sr) * K + k0 + sk, &As[rr * 64]);
      gld_lds16(B + (size_t)(n0 + rr + sr) * K + k0 + sk, &Bs[rr * 64]);
    }
    __syncthreads();
    #pragma unroll
    for (int ks = 0; ks < 2; ++ks) {
      f16x8 af[4], bf[4];
      #pragma unroll
      for (int mt = 0; mt < 4; ++mt)
        af[mt] = *(const f16x8*)&As[(wm * 64 + mt * 16 + (lane & 15)) * 64 + ks * 32 + (lane >> 4) * 8];
      #pragma unroll
      for (int nt = 0; nt < 4; ++nt)
        bf[nt] = *(const f16x8*)&Bs[(wn * 64 + nt * 16 + (lane & 15)) * 64 + ks * 32 + (lane >> 4) * 8];
      #pragma unroll
      for (int mt = 0; mt < 4; ++mt)
        #pragma unroll
        for (int nt = 0; nt < 4; ++nt)
          acc[mt][nt] = __builtin_amdgcn_mfma_f32_16x16x32_f16(af[mt], bf[nt], acc[mt][nt], 0, 0, 0);
    }
  }
  #pragma unroll
  for (int nt = 0; nt < 4; ++nt) {
    int col = n0 + wn * 64 + nt * 16 + (lane & 15);
    float bv = bias[col];
    #pragma unroll
    for (int mt = 0; mt < 4; ++mt) {
      int row = m0 + wm * 64 + mt * 16 + (lane >> 4) * 4;
      if (XGOUT) {
        int b = row >> 7, t0 = row & 127;
        float4 v = { acc[mt][nt][0] + bv, acc[mt][nt][1] + bv,
                     acc[mt][nt][2] + bv, acc[mt][nt][3] + bv };
        *(float4*)&C[((size_t)col * 32 + b) * 128 + t0] = v;
      } else {
        #pragma unroll
        for (int p = 0; p < 4; ++p)
          C[(size_t)(row + p) * N + col] = acc[mt][nt][p] + bv;
      }
    }
  }
}

// ---------------- persistent LSTM recurrence (v2) ----------------
// 128 blocks x 256 threads. Block bid owns 8 hidden units j0=bid*8 (32 gate rows).
// W_hh fragments live in VGPRs (wave wid owns k-range wid*256..+256).
// Per step: prefetch XG regs -> stage h via global_load_lds -> MFMA (2x2 accs)
// -> partials to LDS -> all-thread update (c in reg) -> h store -> barrier.
__global__ __launch_bounds__(256, 1) void lstm_kernel(
    const f16* __restrict__ Whh16,   // [4096][1024]
    const float* __restrict__ XG2,   // [g][b][t] : ((g*32)+b)*128+t
    const f16* __restrict__ h0f,     // [32][1024]
    f16* __restrict__ HS,            // [BT][1024] rows = b*128+t
    unsigned int* __restrict__ bar) {// bar[0]=arrive cnt, bar[64]=release flag
  const int bid = blockIdx.x, tid = threadIdx.x;
  const int lane = tid & 63, wid = tid >> 6;
  const int lr = lane & 15, hi = lane >> 4;
  const int j0 = bid * 8;
  __shared__ f16 hl[32][1032];           // +8 halves pad: frag reads ~2-way
  __shared__ float part[4][32][33];

  // preload W fragments (once): wave wid covers k in [wid*256, wid*256+256)
  f16x8 wfrag[2][8];
  #pragma unroll
  for (int rt = 0; rt < 2; ++rt) {
    int i = rt * 16 + lr;                          // local gate row 0..31
    int g = (i >> 3) * HID + j0 + (i & 7);         // global gate row
    #pragma unroll
    for (int kk = 0; kk < 8; ++kk)
      wfrag[rt][kk] = *(const f16x8*)(Whh16 + (size_t)g * HID + wid * 256 + kk * 32 + hi * 8);
  }

  const int ub = tid & 7, bb = tid >> 3;           // this thread's (u, b)
  float creg = 0.f;

  for (int t = 0; t < Tt; ++t) {
    // ---- XG prefetch (consumed ~0.5us later in update) ----
    float xg[4];
    #pragma unroll
    for (int q = 0; q < 4; ++q)
      xg[q] = XG2[((size_t)(q * HID + j0 + ub) * 32 + bb) * 128 + t];

    // ---- stage h_{t-1}: wave wid stages rows 8*wid..+8, 2 half-rows each ----
    #pragma unroll
    for (int r = 0; r < 8; ++r) {
      int row = wid * 8 + r;
      const f16* hb = (t == 0) ? (h0f + (size_t)row * HID)
                               : (HS + ((size_t)row * Tt + (t - 1)) * HID);
      gld_lds16(hb + (size_t)lane * 8,       &hl[row][0]);
      gld_lds16(hb + 512 + (size_t)lane * 8, &hl[row][512]);
    }
    __syncthreads();   // drains vmcnt -> hl ready

    // ---- gate MFMA: C[32 gates][32 batches], this wave's k-quarter ----
    {
      f32x4 acc[2][2] = {};
      #pragma unroll
      for (int kk = 0; kk < 8; ++kk) {
        int ko = wid * 256 + kk * 32 + hi * 8;
        f16x8 bf0 = *(const f16x8*)&hl[lr][ko];
        f16x8 bf1 = *(const f16x8*)&hl[16 + lr][ko];
        #pragma unroll
        for (int rt = 0; rt < 2; ++rt) {
          acc[rt][0] = __builtin_amdgcn_mfma_f32_16x16x32_f16(wfrag[rt][kk], bf0, acc[rt][0], 0, 0, 0);
          acc[rt][1] = __builtin_amdgcn_mfma_f32_16x16x32_f16(wfrag[rt][kk], bf1, acc[rt][1], 0, 0, 0);
        }
      }
      #pragma unroll
      for (int rt = 0; rt < 2; ++rt)
        #pragma unroll
        for (int bt = 0; bt < 2; ++bt)
          #pragma unroll
          for (int p = 0; p < 4; ++p)
            part[wid][rt * 16 + hi * 4 + p][bt * 16 + lr] = acc[rt][bt][p];
    }
    __syncthreads();

    // ---- LSTM update: every thread owns (u=ub, b=bb) ----
    {
      float g4[4];
      #pragma unroll
      for (int q = 0; q < 4; ++q) {
        int i = q * 8 + ub;
        g4[q] = xg[q] + part[0][i][bb] + part[1][i][bb] + part[2][i][bb] + part[3][i][bb];
      }
      float ig = 1.f / (1.f + __expf(-g4[0]));
      float fg = 1.f / (1.f + __expf(-g4[1]));
      float gg = tanhf(g4[2]);
      float og = 1.f / (1.f + __expf(-g4[3]));
      creg = fg * creg + ig * gg;
      float h = og * tanhf(creg);
      HS[((size_t)bb * Tt + t) * HID + j0 + ub] = (f16)h;
    }

    // ---- grid barrier: arrive counter + separate release flag ----
    if (t != Tt - 1) {
      __threadfence();         // release this thread's HS stores
      __syncthreads();
      if (tid == 0) {
        __hip_atomic_fetch_add(&bar[0], 1u, __ATOMIC_RELEASE, __HIP_MEMORY_SCOPE_AGENT);
        unsigned tgt = (unsigned)(t + 1);
        if (bid == 0) {
          while (__hip_atomic_load(&bar[0], __ATOMIC_RELAXED, __HIP_MEMORY_SCOPE_AGENT) < (unsigned)NB * tgt)
            __builtin_amdgcn_s_sleep(2);
          (void)__hip_atomic_load(&bar[0], __ATOMIC_ACQUIRE, __HIP_MEMORY_SCOPE_AGENT);
          __hip_atomic_store(&bar[64], tgt, __ATOMIC_RELEASE, __HIP_MEMORY_SCOPE_AGENT);
        } else {
          while (__hip_atomic_load(&bar[64], __ATOMIC_ACQUIRE, __HIP_MEMORY_SCOPE_AGENT) < tgt)
            __builtin_amdgcn_s_sleep(2);
        }
      }
      __syncthreads();
      __threadfence();         // acquire: L1 refresh before next-step h reads
    }
  }
}

extern "C" void kernel_launch(void* const* d_in, const int* in_sizes, int n_in,
                              void* d_out, int out_size, void* d_ws, size_t ws_size,
                              hipStream_t stream) {
  const float* z     = (const float*)d_in[0];
  const int*   x     = (const int*)d_in[1];
  const float* W_h   = (const float*)d_in[2];
  const float* b_h   = (const float*)d_in[3];
  const float* emb   = (const float*)d_in[4];
  const float* W_ih  = (const float*)d_in[5];
  const float* W_hh  = (const float*)d_in[6];
  const float* b_ih  = (const float*)d_in[7];
  const float* b_hh  = (const float*)d_in[8];
  const float* W_out = (const float*)d_in[9];
  const float* b_out = (const float*)d_in[10];
  float* out = (float*)d_out;

  char* ws = (char*)d_ws;
  size_t off = 0;
  auto carve = [&](size_t n) { char* p = ws + off; off += (n + 255) & ~(size_t)255; return p; };
  f16*   E16    = (f16*)carve((size_t)BT * DE * 2);     // 4 MB
  f16*   Wih16  = (f16*)carve((size_t)G4 * DE * 2);     // 4 MB
  f16*   Whh16  = (f16*)carve((size_t)G4 * HID * 2);    // 8 MB
  f16*   Wout16 = (f16*)carve((size_t)VOC * HID * 2);   // 64 MB
  float* XG2    = (float*)carve((size_t)BT * G4 * 4);   // 64 MB, [g][b][t]
  f16*   HS     = (f16*)carve((size_t)BT * HID * 2);    // 8 MB
  f16*   h0f    = (f16*)carve((size_t)Bb * HID * 2);
  float* bs     = (float*)carve((size_t)G4 * 4);
  unsigned* bar = (unsigned*)carve(512);

  hipMemsetAsync(bar, 0, 512, stream);   // reset grid barrier each call

  cvt_kernel<<<2048, 256, 0, stream>>>(W_ih,  Wih16,  G4 * DE / 4);
  cvt_kernel<<<2048, 256, 0, stream>>>(W_hh,  Whh16,  G4 * HID / 4);
  cvt_kernel<<<2048, 256, 0, stream>>>(W_out, Wout16, VOC * HID / 4);
  gather_kernel<<<BT * DE / 8 / 256, 256, 0, stream>>>(emb, x, E16);
  bsum_kernel<<<16, 256, 0, stream>>>(b_ih, b_hh, bs, G4);
  h0_kernel<<<128, 256, 0, stream>>>(z, W_h, b_h, h0f);

  dim3 g1(G4 / 128, BT / 128);     // 32 x 32
  gemm_kernel<true><<<g1, 256, 0, stream>>>(E16, Wih16, bs, XG2, BT, G4, DE);

  lstm_kernel<<<NB, 256, 0, stream>>>(Whh16, XG2, h0f, HS, bar);

  dim3 g2(VOC / 128, BT / 128);    // 250 x 32
  gemm_kernel<false><<<g2, 256, 0, stream>>>(HS, Wout16, b_out, out, BT, VOC, HID);
}

// Round 4
// 3058.304 us; speedup vs baseline: 1.9414x; 1.1796x over previous
//
#include <hip/hip_runtime.h>

typedef _Float16 f16;
typedef _Float16 f16x8 __attribute__((ext_vector_type(8)));
typedef _Float16 f16x4 __attribute__((ext_vector_type(4)));
typedef float    f32x4 __attribute__((ext_vector_type(4)));

static constexpr int Bb  = 32;
static constexpr int Tt  = 128;
static constexpr int HID = 1024;
static constexpr int ZD  = 256;
static constexpr int DE  = 512;
static constexpr int VOC = 32000;
static constexpr int BT  = Bb * Tt;   // 4096
static constexpr int G4  = 4 * HID;   // 4096
static constexpr int NB  = 128;       // lstm blocks (8 hidden units each)

// ---- async global->LDS, 16B per lane; LDS dest = wave-uniform base + lane*16 ----
__device__ __forceinline__ void gld_lds16(const void* g, void* l) {
  __builtin_amdgcn_global_load_lds((const __attribute__((address_space(1))) unsigned int*)g,
                                   (__attribute__((address_space(3))) unsigned int*)l,
                                   16, 0, 0);
}

// ---------------- f32 -> f16 convert (vectorized) ----------------
__global__ void cvt_kernel(const float* __restrict__ s, f16* __restrict__ d, int n4) {
  int i = blockIdx.x * blockDim.x + threadIdx.x;
  int st = gridDim.x * blockDim.x;
  for (; i < n4; i += st) {
    float4 v = ((const float4*)s)[i];
    f16x4 o = { (f16)v.x, (f16)v.y, (f16)v.z, (f16)v.w };
    ((f16x4*)d)[i] = o;
  }
}

// ---------------- embedding gather -> f16 ----------------
__global__ void gather_kernel(const float* __restrict__ emb, const int* __restrict__ x,
                              f16* __restrict__ E) {
  int g = blockIdx.x * 256 + threadIdx.x;   // BT*DE/8 threads
  int m = g >> 6, seg = (g & 63) * 8;
  int idx = x[m];
  const float* src = emb + (size_t)idx * DE + seg;
  float4 a = *(const float4*)src;
  float4 b = *(const float4*)(src + 4);
  f16x8 o = { (f16)a.x,(f16)a.y,(f16)a.z,(f16)a.w,(f16)b.x,(f16)b.y,(f16)b.z,(f16)b.w };
  *(f16x8*)(E + (size_t)m * DE + seg) = o;
}

// ---------------- bias sum ----------------
__global__ void bsum_kernel(const float* __restrict__ a, const float* __restrict__ b,
                            float* __restrict__ o, int n) {
  int i = blockIdx.x * blockDim.x + threadIdx.x;
  if (i < n) o[i] = a[i] + b[i];
}

// ---------------- h0 = tanh(z @ W_h^T + b_h), store f16 ----------------
__global__ __launch_bounds__(256) void h0_kernel(const float* __restrict__ z,
                                                 const float* __restrict__ W_h,
                                                 const float* __restrict__ b_h,
                                                 f16* __restrict__ h0f) {
  __shared__ float zs[32][260];
  __shared__ float wsl[8][260];
  const int jc = blockIdx.x, tid = threadIdx.x;
  #pragma unroll
  for (int it = 0; it < 8; ++it) {
    int idx = it * 256 + tid;
    float4 v = ((const float4*)z)[idx];
    int b = idx >> 6, k = (idx & 63) * 4;
    zs[b][k] = v.x; zs[b][k+1] = v.y; zs[b][k+2] = v.z; zs[b][k+3] = v.w;
  }
  #pragma unroll
  for (int it = 0; it < 2; ++it) {
    int idx = it * 256 + tid;
    float4 v = ((const float4*)(W_h + (size_t)jc * 8 * ZD))[idx];
    int r = idx >> 6, k = (idx & 63) * 4;
    wsl[r][k] = v.x; wsl[r][k+1] = v.y; wsl[r][k+2] = v.z; wsl[r][k+3] = v.w;
  }
  __syncthreads();
  const int b = tid >> 3, jj = tid & 7;
  const int j = jc * 8 + jj;
  float acc = b_h[j];
  for (int k = 0; k < ZD; ++k) acc += zs[b][k] * wsl[jj][k];
  h0f[(size_t)b * HID + j] = (f16)tanhf(acc);
}

// ---------------- GEMM: C = A[M,K] @ B[N,K]^T + bias[N]  (f16 in, f32 out) --------
// XGOUT=false: C[row][col] standard.  XGOUT=true: C laid out [g][b][t] float,
// i.e. store at ((col*32 + b)*128 + t) with row = b*128 + t (float4 over t).
template <bool XGOUT>
__global__ __launch_bounds__(256, 2) void gemm_kernel(
    const f16* __restrict__ A, const f16* __restrict__ B,
    const float* __restrict__ bias, float* __restrict__ C,
    int M, int N, int K) {
  __shared__ f16 As[128 * 64];
  __shared__ f16 Bs[128 * 64];
  const int n0 = blockIdx.x * 128, m0 = blockIdx.y * 128;
  const int tid = threadIdx.x, wid = tid >> 6, lane = tid & 63;
  const int wm = wid >> 1, wn = wid & 1;
  const int sr = lane >> 3, sk = (lane & 7) * 8;
  f32x4 acc[4][4] = {};
  for (int k0 = 0; k0 < K; k0 += 64) {
    __syncthreads();
    #pragma unroll
    for (int i = 0; i < 4; ++i) {
      int rr = (wid * 4 + i) * 8;
      gld_lds16(A + (size_t)(m0 + rr + sr) * K + k0 + sk, &As[rr * 64]);
      gld_lds16(B + (size_t)(n0 + rr + sr) * K + k0 + sk, &Bs[rr * 64]);
    }
    __syncthreads();
    #pragma unroll
    for (int ks = 0; ks < 2; ++ks) {
      f16x8 af[4], bf[4];
      #pragma unroll
      for (int mt = 0; mt < 4; ++mt)
        af[mt] = *(const f16x8*)&As[(wm * 64 + mt * 16 + (lane & 15)) * 64 + ks * 32 + (lane >> 4) * 8];
      #pragma unroll
      for (int nt = 0; nt < 4; ++nt)
        bf[nt] = *(const f16x8*)&Bs[(wn * 64 + nt * 16 + (lane & 15)) * 64 + ks * 32 + (lane >> 4) * 8];
      #pragma unroll
      for (int mt = 0; mt < 4; ++mt)
        #pragma unroll
        for (int nt = 0; nt < 4; ++nt)
          acc[mt][nt] = __builtin_amdgcn_mfma_f32_16x16x32_f16(af[mt], bf[nt], acc[mt][nt], 0, 0, 0);
    }
  }
  #pragma unroll
  for (int nt = 0; nt < 4; ++nt) {
    int col = n0 + wn * 64 + nt * 16 + (lane & 15);
    float bv = bias[col];
    #pragma unroll
    for (int mt = 0; mt < 4; ++mt) {
      int row = m0 + wm * 64 + mt * 16 + (lane >> 4) * 4;
      if (XGOUT) {
        int b = row >> 7, t0 = row & 127;
        float4 v = { acc[mt][nt][0] + bv, acc[mt][nt][1] + bv,
                     acc[mt][nt][2] + bv, acc[mt][nt][3] + bv };
        *(float4*)&C[((size_t)col * 32 + b) * 128 + t0] = v;
      } else {
        #pragma unroll
        for (int p = 0; p < 4; ++p)
          C[(size_t)(row + p) * N + col] = acc[mt][nt][p] + bv;
      }
    }
  }
}

// ---------------- persistent LSTM recurrence (v3) ----------------
// 128 blocks x 256 threads. Block bid owns 8 hidden units j0=bid*8 (32 gate rows).
// W_hh fragments live in VGPRs. Per step: prefetch XG regs -> stage h via
// global_load_lds -> MFMA (2x2 accs) -> partials to LDS -> all-thread update
// (c in reg) -> h store -> RMW-free flag barrier (per-block flag, all-poll).
__global__ __launch_bounds__(256, 1) void lstm_kernel(
    const f16* __restrict__ Whh16,   // [4096][1024]
    const float* __restrict__ XG2,   // [g][b][t] : ((g*32)+b)*128+t
    const f16* __restrict__ h0f,     // [32][1024]
    f16* __restrict__ HS,            // [BT][1024] rows = b*128+t
    unsigned int* __restrict__ bar) {// bar[0..127]: per-block step flags
  const int bid = blockIdx.x, tid = threadIdx.x;
  const int lane = tid & 63, wid = tid >> 6;
  const int lr = lane & 15, hi = lane >> 4;
  const int j0 = bid * 8;
  __shared__ f16 hl[32][1032];           // +8 halves pad: frag reads ~2-way
  __shared__ float part[4][32][33];

  // preload W fragments (once): wave wid covers k in [wid*256, wid*256+256)
  f16x8 wfrag[2][8];
  #pragma unroll
  for (int rt = 0; rt < 2; ++rt) {
    int i = rt * 16 + lr;                          // local gate row 0..31
    int g = (i >> 3) * HID + j0 + (i & 7);         // global gate row
    #pragma unroll
    for (int kk = 0; kk < 8; ++kk)
      wfrag[rt][kk] = *(const f16x8*)(Whh16 + (size_t)g * HID + wid * 256 + kk * 32 + hi * 8);
  }

  const int ub = tid & 7, bb = tid >> 3;           // this thread's (u, b)
  float creg = 0.f;

  for (int t = 0; t < Tt; ++t) {
    // ---- XG prefetch (consumed after MFMA) ----
    float xg[4];
    #pragma unroll
    for (int q = 0; q < 4; ++q)
      xg[q] = XG2[((size_t)(q * HID + j0 + ub) * 32 + bb) * 128 + t];

    // ---- stage h_{t-1}: wave wid stages rows 8*wid..+8, 2 half-rows each ----
    #pragma unroll
    for (int r = 0; r < 8; ++r) {
      int row = wid * 8 + r;
      const f16* hb = (t == 0) ? (h0f + (size_t)row * HID)
                               : (HS + ((size_t)row * Tt + (t - 1)) * HID);
      gld_lds16(hb + (size_t)lane * 8,       &hl[row][0]);
      gld_lds16(hb + 512 + (size_t)lane * 8, &hl[row][512]);
    }
    __syncthreads();   // drains vmcnt -> hl ready

    // ---- gate MFMA: C[32 gates][32 batches], this wave's k-quarter ----
    {
      f32x4 acc[2][2] = {};
      #pragma unroll
      for (int kk = 0; kk < 8; ++kk) {
        int ko = wid * 256 + kk * 32 + hi * 8;
        f16x8 bf0 = *(const f16x8*)&hl[lr][ko];
        f16x8 bf1 = *(const f16x8*)&hl[16 + lr][ko];
        #pragma unroll
        for (int rt = 0; rt < 2; ++rt) {
          acc[rt][0] = __builtin_amdgcn_mfma_f32_16x16x32_f16(wfrag[rt][kk], bf0, acc[rt][0], 0, 0, 0);
          acc[rt][1] = __builtin_amdgcn_mfma_f32_16x16x32_f16(wfrag[rt][kk], bf1, acc[rt][1], 0, 0, 0);
        }
      }
      #pragma unroll
      for (int rt = 0; rt < 2; ++rt)
        #pragma unroll
        for (int bt = 0; bt < 2; ++bt)
          #pragma unroll
          for (int p = 0; p < 4; ++p)
            part[wid][rt * 16 + hi * 4 + p][bt * 16 + lr] = acc[rt][bt][p];
    }
    __syncthreads();

    // ---- LSTM update: every thread owns (u=ub, b=bb) ----
    {
      float g4[4];
      #pragma unroll
      for (int q = 0; q < 4; ++q) {
        int i = q * 8 + ub;
        g4[q] = xg[q] + part[0][i][bb] + part[1][i][bb] + part[2][i][bb] + part[3][i][bb];
      }
      float ig = 1.f / (1.f + __expf(-g4[0]));
      float fg = 1.f / (1.f + __expf(-g4[1]));
      float gg = tanhf(g4[2]);
      float og = 1.f / (1.f + __expf(-g4[3]));
      creg = fg * creg + ig * gg;
      float h = og * tanhf(creg);
      HS[((size_t)bb * Tt + t) * HID + j0 + ub] = (f16)h;
    }

    // ---- RMW-free grid barrier: own-flag store + all-blocks poll ----
    if (t != Tt - 1) {
      __threadfence();         // release: drain h stores to coherence point
      __syncthreads();
      const unsigned tgt = (unsigned)(t + 1);
      if (wid == 0) {
        if (lane == 0)
          __hip_atomic_store(&bar[bid], tgt, __ATOMIC_RELEASE, __HIP_MEMORY_SCOPE_AGENT);
        // each lane watches 2 of the 128 flags; no RMW, single hop
        for (;;) {
          unsigned a = __hip_atomic_load(&bar[lane],      __ATOMIC_RELAXED, __HIP_MEMORY_SCOPE_AGENT);
          unsigned b = __hip_atomic_load(&bar[64 + lane], __ATOMIC_RELAXED, __HIP_MEMORY_SCOPE_AGENT);
          if (__all((a >= tgt) && (b >= tgt))) break;
        }
      }
      __syncthreads();
      // acquire: fence-atomic sync with the release stores observed above
      __builtin_amdgcn_fence(__ATOMIC_ACQUIRE, "agent");
    }
  }
}

extern "C" void kernel_launch(void* const* d_in, const int* in_sizes, int n_in,
                              void* d_out, int out_size, void* d_ws, size_t ws_size,
                              hipStream_t stream) {
  const float* z     = (const float*)d_in[0];
  const int*   x     = (const int*)d_in[1];
  const float* W_h   = (const float*)d_in[2];
  const float* b_h   = (const float*)d_in[3];
  const float* emb   = (const float*)d_in[4];
  const float* W_ih  = (const float*)d_in[5];
  const float* W_hh  = (const float*)d_in[6];
  const float* b_ih  = (const float*)d_in[7];
  const float* b_hh  = (const float*)d_in[8];
  const float* W_out = (const float*)d_in[9];
  const float* b_out = (const float*)d_in[10];
  float* out = (float*)d_out;

  char* ws = (char*)d_ws;
  size_t off = 0;
  auto carve = [&](size_t n) { char* p = ws + off; off += (n + 255) & ~(size_t)255; return p; };
  f16*   E16    = (f16*)carve((size_t)BT * DE * 2);     // 4 MB
  f16*   Wih16  = (f16*)carve((size_t)G4 * DE * 2);     // 4 MB
  f16*   Whh16  = (f16*)carve((size_t)G4 * HID * 2);    // 8 MB
  f16*   Wout16 = (f16*)carve((size_t)VOC * HID * 2);   // 64 MB
  float* XG2    = (float*)carve((size_t)BT * G4 * 4);   // 64 MB, [g][b][t]
  f16*   HS     = (f16*)carve((size_t)BT * HID * 2);    // 8 MB
  f16*   h0f    = (f16*)carve((size_t)Bb * HID * 2);
  float* bs     = (float*)carve((size_t)G4 * 4);
  unsigned* bar = (unsigned*)carve(512);

  (void)hipMemsetAsync(bar, 0, 512, stream);   // reset grid barrier flags each call

  cvt_kernel<<<2048, 256, 0, stream>>>(W_ih,  Wih16,  G4 * DE / 4);
  cvt_kernel<<<2048, 256, 0, stream>>>(W_hh,  Whh16,  G4 * HID / 4);
  cvt_kernel<<<2048, 256, 0, stream>>>(W_out, Wout16, VOC * HID / 4);
  gather_kernel<<<BT * DE / 8 / 256, 256, 0, stream>>>(emb, x, E16);
  bsum_kernel<<<16, 256, 0, stream>>>(b_ih, b_hh, bs, G4);
  h0_kernel<<<128, 256, 0, stream>>>(z, W_h, b_h, h0f);

  dim3 g1(G4 / 128, BT / 128);     // 32 x 32
  gemm_kernel<true><<<g1, 256, 0, stream>>>(E16, Wih16, bs, XG2, BT, G4, DE);

  lstm_kernel<<<NB, 256, 0, stream>>>(Whh16, XG2, h0f, HS, bar);

  dim3 g2(VOC / 128, BT / 128);    // 250 x 32
  gemm_kernel<false><<<g2, 256, 0, stream>>>(HS, Wout16, b_out, out, BT, VOC, HID);
}

// Round 5
// 1183.158 us; speedup vs baseline: 5.0182x; 2.5849x over previous
//
#include <hip/hip_runtime.h>

typedef _Float16 f16;
typedef _Float16 f16x8 __attribute__((ext_vector_type(8)));
typedef _Float16 f16x4 __attribute__((ext_vector_type(4)));
typedef float    f32x4 __attribute__((ext_vector_type(4)));

static constexpr int Bb  = 32;
static constexpr int Tt  = 128;
static constexpr int HID = 1024;
static constexpr int ZD  = 256;
static constexpr int DE  = 512;
static constexpr int VOC = 32000;
static constexpr int BT  = Bb * Tt;   // 4096
static constexpr int G4  = 4 * HID;   // 4096
static constexpr int NB  = 64;        // lstm blocks (16 hidden units each)

// ---- async global->LDS, 16B per lane; LDS dest = wave-uniform base + lane*16 ----
__device__ __forceinline__ void gld_lds16(const void* g, void* l) {
  __builtin_amdgcn_global_load_lds((const __attribute__((address_space(1))) unsigned int*)g,
                                   (__attribute__((address_space(3))) unsigned int*)l,
                                   16, 0, 0);
}

// ---------------- f32 -> f16 convert (vectorized) ----------------
__global__ void cvt_kernel(const float* __restrict__ s, f16* __restrict__ d, int n4) {
  int i = blockIdx.x * blockDim.x + threadIdx.x;
  int st = gridDim.x * blockDim.x;
  for (; i < n4; i += st) {
    float4 v = ((const float4*)s)[i];
    f16x4 o = { (f16)v.x, (f16)v.y, (f16)v.z, (f16)v.w };
    ((f16x4*)d)[i] = o;
  }
}

// ---------------- embedding gather -> f16 ----------------
__global__ void gather_kernel(const float* __restrict__ emb, const int* __restrict__ x,
                              f16* __restrict__ E) {
  int g = blockIdx.x * 256 + threadIdx.x;   // BT*DE/8 threads
  int m = g >> 6, seg = (g & 63) * 8;
  int idx = x[m];
  const float* src = emb + (size_t)idx * DE + seg;
  float4 a = *(const float4*)src;
  float4 b = *(const float4*)(src + 4);
  f16x8 o = { (f16)a.x,(f16)a.y,(f16)a.z,(f16)a.w,(f16)b.x,(f16)b.y,(f16)b.z,(f16)b.w };
  *(f16x8*)(E + (size_t)m * DE + seg) = o;
}

// ---------------- bias sum ----------------
__global__ void bsum_kernel(const float* __restrict__ a, const float* __restrict__ b,
                            float* __restrict__ o, int n) {
  int i = blockIdx.x * blockDim.x + threadIdx.x;
  if (i < n) o[i] = a[i] + b[i];
}

// ---------------- h0 = tanh(z @ W_h^T + b_h), store f16 ----------------
__global__ __launch_bounds__(256) void h0_kernel(const float* __restrict__ z,
                                                 const float* __restrict__ W_h,
                                                 const float* __restrict__ b_h,
                                                 f16* __restrict__ h0f) {
  __shared__ float zs[32][260];
  __shared__ float wsl[8][260];
  const int jc = blockIdx.x, tid = threadIdx.x;
  #pragma unroll
  for (int it = 0; it < 8; ++it) {
    int idx = it * 256 + tid;
    float4 v = ((const float4*)z)[idx];
    int b = idx >> 6, k = (idx & 63) * 4;
    zs[b][k] = v.x; zs[b][k+1] = v.y; zs[b][k+2] = v.z; zs[b][k+3] = v.w;
  }
  #pragma unroll
  for (int it = 0; it < 2; ++it) {
    int idx = it * 256 + tid;
    float4 v = ((const float4*)(W_h + (size_t)jc * 8 * ZD))[idx];
    int r = idx >> 6, k = (idx & 63) * 4;
    wsl[r][k] = v.x; wsl[r][k+1] = v.y; wsl[r][k+2] = v.z; wsl[r][k+3] = v.w;
  }
  __syncthreads();
  const int b = tid >> 3, jj = tid & 7;
  const int j = jc * 8 + jj;
  float acc = b_h[j];
  for (int k = 0; k < ZD; ++k) acc += zs[b][k] * wsl[jj][k];
  h0f[(size_t)b * HID + j] = (f16)tanhf(acc);
}

// ---------------- GEMM: C = A[M,K] @ B[N,K]^T + bias[N]  (f16 in, f32 out) --------
// XGOUT=false: C[row][col] standard.  XGOUT=true: C laid out [g][b][t] float,
// i.e. store at ((col*32 + b)*128 + t) with row = b*128 + t (float4 over t).
template <bool XGOUT>
__global__ __launch_bounds__(256, 2) void gemm_kernel(
    const f16* __restrict__ A, const f16* __restrict__ B,
    const float* __restrict__ bias, float* __restrict__ C,
    int M, int N, int K) {
  __shared__ f16 As[128 * 64];
  __shared__ f16 Bs[128 * 64];
  const int n0 = blockIdx.x * 128, m0 = blockIdx.y * 128;
  const int tid = threadIdx.x, wid = tid >> 6, lane = tid & 63;
  const int wm = wid >> 1, wn = wid & 1;
  const int sr = lane >> 3, sk = (lane & 7) * 8;
  f32x4 acc[4][4] = {};
  for (int k0 = 0; k0 < K; k0 += 64) {
    __syncthreads();
    #pragma unroll
    for (int i = 0; i < 4; ++i) {
      int rr = (wid * 4 + i) * 8;
      gld_lds16(A + (size_t)(m0 + rr + sr) * K + k0 + sk, &As[rr * 64]);
      gld_lds16(B + (size_t)(n0 + rr + sr) * K + k0 + sk, &Bs[rr * 64]);
    }
    __syncthreads();
    #pragma unroll
    for (int ks = 0; ks < 2; ++ks) {
      f16x8 af[4], bf[4];
      #pragma unroll
      for (int mt = 0; mt < 4; ++mt)
        af[mt] = *(const f16x8*)&As[(wm * 64 + mt * 16 + (lane & 15)) * 64 + ks * 32 + (lane >> 4) * 8];
      #pragma unroll
      for (int nt = 0; nt < 4; ++nt)
        bf[nt] = *(const f16x8*)&Bs[(wn * 64 + nt * 16 + (lane & 15)) * 64 + ks * 32 + (lane >> 4) * 8];
      #pragma unroll
      for (int mt = 0; mt < 4; ++mt)
        #pragma unroll
        for (int nt = 0; nt < 4; ++nt)
          acc[mt][nt] = __builtin_amdgcn_mfma_f32_16x16x32_f16(af[mt], bf[nt], acc[mt][nt], 0, 0, 0);
    }
  }
  #pragma unroll
  for (int nt = 0; nt < 4; ++nt) {
    int col = n0 + wn * 64 + nt * 16 + (lane & 15);
    float bv = bias[col];
    #pragma unroll
    for (int mt = 0; mt < 4; ++mt) {
      int row = m0 + wm * 64 + mt * 16 + (lane >> 4) * 4;
      if (XGOUT) {
        int b = row >> 7, t0 = row & 127;
        float4 v = { acc[mt][nt][0] + bv, acc[mt][nt][1] + bv,
                     acc[mt][nt][2] + bv, acc[mt][nt][3] + bv };
        *(float4*)&C[((size_t)col * 32 + b) * 128 + t0] = v;
      } else {
        #pragma unroll
        for (int p = 0; p < 4; ++p)
          C[(size_t)(row + p) * N + col] = acc[mt][nt][p] + bv;
      }
    }
  }
}

// ---------------- persistent LSTM recurrence (v4: fence-free) ----------------
// 64 blocks x 512 threads (8 waves). Block bid owns 16 hidden units (64 gate rows).
// W_hh fragments in VGPRs (wave wid owns k-range wid*128..+128).
// ALL cross-block data (HS, bar) moves via agent-scope atomics (sc0|sc1: bypass
// the non-coherent XCD L2) -> NO threadfence / wbl2 / buffer_inv anywhere, and
// XG2/Whh stay L2-resident across steps (each 128B XG line serves 32 steps).
__global__ __launch_bounds__(512, 1) void lstm_kernel(
    const f16* __restrict__ Whh16,   // [4096][1024]
    const float* __restrict__ XG2,   // [g][b][t] : ((g*32)+b)*128+t
    const f16* __restrict__ h0f,     // [32][1024]
    f16* __restrict__ HS,            // [BT][1024] rows = b*128+t
    unsigned int* __restrict__ bar) {// bar[0..63]: per-block completed-step flags
  const int bid = blockIdx.x, tid = threadIdx.x;
  const int lane = tid & 63, wid = tid >> 6;
  const int lr = lane & 15, hi = lane >> 4;
  const int j0 = bid * 16;
  __shared__ f16 hl[32][1032];           // batch-major h tile, +8 halves pad
  __shared__ float part[8][64][33];      // per-wave K-partials

  // preload W fragments (once): wave wid covers k in [wid*128, wid*128+128)
  f16x8 wfrag[4][4];
  #pragma unroll
  for (int rt = 0; rt < 4; ++rt) {                 // rt = gate q; row u = lr
    int g = rt * HID + j0 + lr;
    #pragma unroll
    for (int kk = 0; kk < 4; ++kk)
      wfrag[rt][kk] = *(const f16x8*)(Whh16 + (size_t)g * HID + wid * 128 + kk * 32 + hi * 8);
  }

  const int ub = tid & 15, bb = tid >> 4;          // thread owns (unit ub, batch bb)
  float creg = 0.f;

  for (int t = 0; t < Tt; ++t) {
    // ---- XG prefetch (normal cached loads; line holds 32 t-values -> L2 hits) ----
    float xg[4];
    #pragma unroll
    for (int q = 0; q < 4; ++q)
      xg[q] = XG2[((size_t)(q * HID + j0 + ub) * 32 + bb) * 128 + t];

    // ---- wait for all 64 blocks to have posted h_{t-1} (per-wave poll) ----
    if (t > 0) {
      const unsigned tgt = (unsigned)t;
      for (;;) {
        unsigned f = __hip_atomic_load(&bar[lane], __ATOMIC_RELAXED, __HIP_MEMORY_SCOPE_AGENT);
        if (__all(f >= tgt)) break;
      }
    }

    // ---- stage h_{t-1}: wave wid loads batch rows 4*wid..+4 (coherent 8B loads) ----
    {
      unsigned long long tmp[4][4];
      #pragma unroll
      for (int r = 0; r < 4; ++r) {
        int row = wid * 4 + r;
        const f16* hb = (t == 0) ? (h0f + (size_t)row * HID)
                                 : (HS + ((size_t)row * Tt + (t - 1)) * HID);
        #pragma unroll
        for (int c = 0; c < 4; ++c)
          tmp[r][c] = __hip_atomic_load((const unsigned long long*)hb + c * 64 + lane,
                                        __ATOMIC_RELAXED, __HIP_MEMORY_SCOPE_AGENT);
      }
      #pragma unroll
      for (int r = 0; r < 4; ++r) {
        int row = wid * 4 + r;
        #pragma unroll
        for (int c = 0; c < 4; ++c)
          *(unsigned long long*)&hl[row][(c * 64 + lane) * 4] = tmp[r][c];
      }
    }
    __syncthreads();

    // ---- gate MFMA: C[64 gate rows][32 batches], this wave's k-eighth ----
    {
      f32x4 acc[4][2] = {};
      #pragma unroll
      for (int kk = 0; kk < 4; ++kk) {
        int ko = wid * 128 + kk * 32 + hi * 8;
        f16x8 bf0 = *(const f16x8*)&hl[lr][ko];
        f16x8 bf1 = *(const f16x8*)&hl[16 + lr][ko];
        #pragma unroll
        for (int rt = 0; rt < 4; ++rt) {
          acc[rt][0] = __builtin_amdgcn_mfma_f32_16x16x32_f16(wfrag[rt][kk], bf0, acc[rt][0], 0, 0, 0);
          acc[rt][1] = __builtin_amdgcn_mfma_f32_16x16x32_f16(wfrag[rt][kk], bf1, acc[rt][1], 0, 0, 0);
        }
      }
      #pragma unroll
      for (int rt = 0; rt < 4; ++rt)
        #pragma unroll
        for (int bt = 0; bt < 2; ++bt)
          #pragma unroll
          for (int p = 0; p < 4; ++p)
            part[wid][rt * 16 + hi * 4 + p][bt * 16 + lr] = acc[rt][bt][p];
    }
    __syncthreads();

    // ---- LSTM update: thread (ub, bb); h store is agent-coherent 2B ----
    {
      float g4[4];
      #pragma unroll
      for (int q = 0; q < 4; ++q) {
        int i = q * 16 + ub;
        float s = xg[q];
        #pragma unroll
        for (int w = 0; w < 8; ++w) s += part[w][i][bb];
        g4[q] = s;
      }
      float ig = 1.f / (1.f + __expf(-g4[0]));
      float fg = 1.f / (1.f + __expf(-g4[1]));
      float gg = tanhf(g4[2]);
      float og = 1.f / (1.f + __expf(-g4[3]));
      creg = fg * creg + ig * gg;
      float h = og * tanhf(creg);
      union { f16 h; unsigned short u; } cv;
      cv.h = (f16)h;
      __hip_atomic_store((unsigned short*)&HS[((size_t)bb * Tt + t) * HID + j0 + ub],
                         cv.u, __ATOMIC_RELAXED, __HIP_MEMORY_SCOPE_AGENT);
    }

    // ---- post completion flag (no fences: waitcnt + barrier order the stores) ----
    if (t != Tt - 1) {
      asm volatile("s_waitcnt vmcnt(0)" ::: "memory");  // my h stores are at IF
      __syncthreads();                                  // => all threads' are
      if (tid == 0)
        __hip_atomic_store(&bar[bid], (unsigned)(t + 1),
                           __ATOMIC_RELAXED, __HIP_MEMORY_SCOPE_AGENT);
    }
  }
}

extern "C" void kernel_launch(void* const* d_in, const int* in_sizes, int n_in,
                              void* d_out, int out_size, void* d_ws, size_t ws_size,
                              hipStream_t stream) {
  const float* z     = (const float*)d_in[0];
  const int*   x     = (const int*)d_in[1];
  const float* W_h   = (const float*)d_in[2];
  const float* b_h   = (const float*)d_in[3];
  const float* emb   = (const float*)d_in[4];
  const float* W_ih  = (const float*)d_in[5];
  const float* W_hh  = (const float*)d_in[6];
  const float* b_ih  = (const float*)d_in[7];
  const float* b_hh  = (const float*)d_in[8];
  const float* W_out = (const float*)d_in[9];
  const float* b_out = (const float*)d_in[10];
  float* out = (float*)d_out;

  char* ws = (char*)d_ws;
  size_t off = 0;
  auto carve = [&](size_t n) { char* p = ws + off; off += (n + 255) & ~(size_t)255; return p; };
  f16*   E16    = (f16*)carve((size_t)BT * DE * 2);     // 4 MB
  f16*   Wih16  = (f16*)carve((size_t)G4 * DE * 2);     // 4 MB
  f16*   Whh16  = (f16*)carve((size_t)G4 * HID * 2);    // 8 MB
  f16*   Wout16 = (f16*)carve((size_t)VOC * HID * 2);   // 64 MB
  float* XG2    = (float*)carve((size_t)BT * G4 * 4);   // 64 MB, [g][b][t]
  f16*   HS     = (f16*)carve((size_t)BT * HID * 2);    // 8 MB
  f16*   h0f    = (f16*)carve((size_t)Bb * HID * 2);
  float* bs     = (float*)carve((size_t)G4 * 4);
  unsigned* bar = (unsigned*)carve(256);

  (void)hipMemsetAsync(bar, 0, 256, stream);   // reset grid flags each call

  cvt_kernel<<<2048, 256, 0, stream>>>(W_ih,  Wih16,  G4 * DE / 4);
  cvt_kernel<<<2048, 256, 0, stream>>>(W_hh,  Whh16,  G4 * HID / 4);
  cvt_kernel<<<2048, 256, 0, stream>>>(W_out, Wout16, VOC * HID / 4);
  gather_kernel<<<BT * DE / 8 / 256, 256, 0, stream>>>(emb, x, E16);
  bsum_kernel<<<16, 256, 0, stream>>>(b_ih, b_hh, bs, G4);
  h0_kernel<<<128, 256, 0, stream>>>(z, W_h, b_h, h0f);

  dim3 g1(G4 / 128, BT / 128);     // 32 x 32
  gemm_kernel<true><<<g1, 256, 0, stream>>>(E16, Wih16, bs, XG2, BT, G4, DE);

  lstm_kernel<<<NB, 512, 0, stream>>>(Whh16, XG2, h0f, HS, bar);

  dim3 g2(VOC / 128, BT / 128);    // 250 x 32
  gemm_kernel<false><<<g2, 256, 0, stream>>>(HS, Wout16, b_out, out, BT, VOC, HID);
}

// Round 6
// 1112.910 us; speedup vs baseline: 5.3349x; 1.0631x over previous
//
#include <hip/hip_runtime.h>

typedef _Float16 f16;
typedef _Float16 f16x8 __attribute__((ext_vector_type(8)));
typedef _Float16 f16x4 __attribute__((ext_vector_type(4)));
typedef float    f32x4 __attribute__((ext_vector_type(4)));

static constexpr int Bb  = 32;
static constexpr int Tt  = 128;
static constexpr int HID = 1024;
static constexpr int ZD  = 256;
static constexpr int DE  = 512;
static constexpr int VOC = 32000;
static constexpr int BT  = Bb * Tt;   // 4096
static constexpr int G4  = 4 * HID;   // 4096
static constexpr int NB  = 64;        // lstm blocks (16 hidden units each)

// ---- async global->LDS, 16B per lane; LDS dest = wave-uniform base + lane*16 ----
__device__ __forceinline__ void gld_lds16(const void* g, void* l) {
  __builtin_amdgcn_global_load_lds((const __attribute__((address_space(1))) unsigned int*)g,
                                   (__attribute__((address_space(3))) unsigned int*)l,
                                   16, 0, 0);
}

// ---------------- f32 -> f16 convert (vectorized) ----------------
__global__ void cvt_kernel(const float* __restrict__ s, f16* __restrict__ d, int n4) {
  int i = blockIdx.x * blockDim.x + threadIdx.x;
  int st = gridDim.x * blockDim.x;
  for (; i < n4; i += st) {
    float4 v = ((const float4*)s)[i];
    f16x4 o = { (f16)v.x, (f16)v.y, (f16)v.z, (f16)v.w };
    ((f16x4*)d)[i] = o;
  }
}

// ---------------- embedding gather -> f16 ----------------
__global__ void gather_kernel(const float* __restrict__ emb, const int* __restrict__ x,
                              f16* __restrict__ E) {
  int g = blockIdx.x * 256 + threadIdx.x;   // BT*DE/8 threads
  int m = g >> 6, seg = (g & 63) * 8;
  int idx = x[m];
  const float* src = emb + (size_t)idx * DE + seg;
  float4 a = *(const float4*)src;
  float4 b = *(const float4*)(src + 4);
  f16x8 o = { (f16)a.x,(f16)a.y,(f16)a.z,(f16)a.w,(f16)b.x,(f16)b.y,(f16)b.z,(f16)b.w };
  *(f16x8*)(E + (size_t)m * DE + seg) = o;
}

// ---------------- bias sum ----------------
__global__ void bsum_kernel(const float* __restrict__ a, const float* __restrict__ b,
                            float* __restrict__ o, int n) {
  int i = blockIdx.x * blockDim.x + threadIdx.x;
  if (i < n) o[i] = a[i] + b[i];
}

// ---------------- h0 = tanh(z @ W_h^T + b_h), store f16 ----------------
__global__ __launch_bounds__(256) void h0_kernel(const float* __restrict__ z,
                                                 const float* __restrict__ W_h,
                                                 const float* __restrict__ b_h,
                                                 f16* __restrict__ h0f) {
  __shared__ float zs[32][260];
  __shared__ float wsl[8][260];
  const int jc = blockIdx.x, tid = threadIdx.x;
  #pragma unroll
  for (int it = 0; it < 8; ++it) {
    int idx = it * 256 + tid;
    float4 v = ((const float4*)z)[idx];
    int b = idx >> 6, k = (idx & 63) * 4;
    zs[b][k] = v.x; zs[b][k+1] = v.y; zs[b][k+2] = v.z; zs[b][k+3] = v.w;
  }
  #pragma unroll
  for (int it = 0; it < 2; ++it) {
    int idx = it * 256 + tid;
    float4 v = ((const float4*)(W_h + (size_t)jc * 8 * ZD))[idx];
    int r = idx >> 6, k = (idx & 63) * 4;
    wsl[r][k] = v.x; wsl[r][k+1] = v.y; wsl[r][k+2] = v.z; wsl[r][k+3] = v.w;
  }
  __syncthreads();
  const int b = tid >> 3, jj = tid & 7;
  const int j = jc * 8 + jj;
  float acc = b_h[j];
  for (int k = 0; k < ZD; ++k) acc += zs[b][k] * wsl[jj][k];
  h0f[(size_t)b * HID + j] = (f16)tanhf(acc);
}

// ---------------- GEMM: C = A[M,K] @ B[N,K]^T + bias[N]  (f16 in, f32 out) --------
// XGOUT=false: C[row][col] standard.  XGOUT=true: C laid out [g][b][t] float,
// i.e. store at ((col*32 + b)*128 + t) with row = b*128 + t (float4 over t).
template <bool XGOUT>
__global__ __launch_bounds__(256, 2) void gemm_kernel(
    const f16* __restrict__ A, const f16* __restrict__ B,
    const float* __restrict__ bias, float* __restrict__ C,
    int M, int N, int K) {
  __shared__ f16 As[128 * 64];
  __shared__ f16 Bs[128 * 64];
  const int n0 = blockIdx.x * 128, m0 = blockIdx.y * 128;
  const int tid = threadIdx.x, wid = tid >> 6, lane = tid & 63;
  const int wm = wid >> 1, wn = wid & 1;
  const int sr = lane >> 3, sk = (lane & 7) * 8;
  f32x4 acc[4][4] = {};
  for (int k0 = 0; k0 < K; k0 += 64) {
    __syncthreads();
    #pragma unroll
    for (int i = 0; i < 4; ++i) {
      int rr = (wid * 4 + i) * 8;
      gld_lds16(A + (size_t)(m0 + rr + sr) * K + k0 + sk, &As[rr * 64]);
      gld_lds16(B + (size_t)(n0 + rr + sr) * K + k0 + sk, &Bs[rr * 64]);
    }
    __syncthreads();
    #pragma unroll
    for (int ks = 0; ks < 2; ++ks) {
      f16x8 af[4], bf[4];
      #pragma unroll
      for (int mt = 0; mt < 4; ++mt)
        af[mt] = *(const f16x8*)&As[(wm * 64 + mt * 16 + (lane & 15)) * 64 + ks * 32 + (lane >> 4) * 8];
      #pragma unroll
      for (int nt = 0; nt < 4; ++nt)
        bf[nt] = *(const f16x8*)&Bs[(wn * 64 + nt * 16 + (lane & 15)) * 64 + ks * 32 + (lane >> 4) * 8];
      #pragma unroll
      for (int mt = 0; mt < 4; ++mt)
        #pragma unroll
        for (int nt = 0; nt < 4; ++nt)
          acc[mt][nt] = __builtin_amdgcn_mfma_f32_16x16x32_f16(af[mt], bf[nt], acc[mt][nt], 0, 0, 0);
    }
  }
  #pragma unroll
  for (int nt = 0; nt < 4; ++nt) {
    int col = n0 + wn * 64 + nt * 16 + (lane & 15);
    float bv = bias[col];
    #pragma unroll
    for (int mt = 0; mt < 4; ++mt) {
      int row = m0 + wm * 64 + mt * 16 + (lane >> 4) * 4;
      if (XGOUT) {
        int b = row >> 7, t0 = row & 127;
        float4 v = { acc[mt][nt][0] + bv, acc[mt][nt][1] + bv,
                     acc[mt][nt][2] + bv, acc[mt][nt][3] + bv };
        *(float4*)&C[((size_t)col * 32 + b) * 128 + t0] = v;
      } else {
        #pragma unroll
        for (int p = 0; p < 4; ++p)
          C[(size_t)(row + p) * N + col] = acc[mt][nt][p] + bv;
      }
    }
  }
}

// ---------------- persistent LSTM recurrence (v5: fence-free, 1-wave poll) --------
// 64 blocks x 512 threads (8 waves). Block bid owns 16 hidden units (64 gate rows).
// W_hh fragments in VGPRs (wave wid owns k-range wid*128..+128).
// Cross-block data (HS, bar) moves via agent-scope atomics (bypass non-coherent
// XCD L2) -> no fences/wbl2/buffer_inv; XG2/Whh stay L2-resident across steps.
// v5: ONLY WAVE 0 polls the flags (64 polling waves grid-wide, not 512) to cut
// reader contention at the IF coherence point during store visibility.
__global__ __launch_bounds__(512, 1) void lstm_kernel(
    const f16* __restrict__ Whh16,   // [4096][1024]
    const float* __restrict__ XG2,   // [g][b][t] : ((g*32)+b)*128+t
    const f16* __restrict__ h0f,     // [32][1024]
    f16* __restrict__ HS,            // [BT][1024] rows = b*128+t
    unsigned int* __restrict__ bar) {// bar[0..63]: per-block completed-step flags
  const int bid = blockIdx.x, tid = threadIdx.x;
  const int lane = tid & 63, wid = tid >> 6;
  const int lr = lane & 15, hi = lane >> 4;
  const int j0 = bid * 16;
  __shared__ f16 hl[32][1032];           // batch-major h tile, +8 halves pad
  __shared__ float part[8][64][33];      // per-wave K-partials

  // preload W fragments (once): wave wid covers k in [wid*128, wid*128+128)
  f16x8 wfrag[4][4];
  #pragma unroll
  for (int rt = 0; rt < 4; ++rt) {                 // rt = gate q; row u = lr
    int g = rt * HID + j0 + lr;
    #pragma unroll
    for (int kk = 0; kk < 4; ++kk)
      wfrag[rt][kk] = *(const f16x8*)(Whh16 + (size_t)g * HID + wid * 128 + kk * 32 + hi * 8);
  }

  const int ub = tid & 15, bb = tid >> 4;          // thread owns (unit ub, batch bb)
  float creg = 0.f;

  for (int t = 0; t < Tt; ++t) {
    // ---- XG prefetch (normal cached loads; line holds 32 t-values -> L2 hits) ----
    float xg[4];
    #pragma unroll
    for (int q = 0; q < 4; ++q)
      xg[q] = XG2[((size_t)(q * HID + j0 + ub) * 32 + bb) * 128 + t];

    // ---- wait for all 64 blocks' h_{t-1}: wave 0 polls, barrier releases rest ----
    if (t > 0) {
      if (wid == 0) {
        const unsigned tgt = (unsigned)t;
        for (;;) {
          unsigned f = __hip_atomic_load(&bar[lane], __ATOMIC_RELAXED, __HIP_MEMORY_SCOPE_AGENT);
          if (__all(f >= tgt)) break;
        }
      }
      __syncthreads();
    }

    // ---- stage h_{t-1}: wave wid loads batch rows 4*wid..+4 (coherent 8B loads) ----
    {
      unsigned long long tmp[4][4];
      #pragma unroll
      for (int r = 0; r < 4; ++r) {
        int row = wid * 4 + r;
        const f16* hb = (t == 0) ? (h0f + (size_t)row * HID)
                                 : (HS + ((size_t)row * Tt + (t - 1)) * HID);
        #pragma unroll
        for (int c = 0; c < 4; ++c)
          tmp[r][c] = __hip_atomic_load((const unsigned long long*)hb + c * 64 + lane,
                                        __ATOMIC_RELAXED, __HIP_MEMORY_SCOPE_AGENT);
      }
      #pragma unroll
      for (int r = 0; r < 4; ++r) {
        int row = wid * 4 + r;
        #pragma unroll
        for (int c = 0; c < 4; ++c)
          *(unsigned long long*)&hl[row][(c * 64 + lane) * 4] = tmp[r][c];
      }
    }
    __syncthreads();

    // ---- gate MFMA: C[64 gate rows][32 batches], this wave's k-eighth ----
    {
      f32x4 acc[4][2] = {};
      #pragma unroll
      for (int kk = 0; kk < 4; ++kk) {
        int ko = wid * 128 + kk * 32 + hi * 8;
        f16x8 bf0 = *(const f16x8*)&hl[lr][ko];
        f16x8 bf1 = *(const f16x8*)&hl[16 + lr][ko];
        #pragma unroll
        for (int rt = 0; rt < 4; ++rt) {
          acc[rt][0] = __builtin_amdgcn_mfma_f32_16x16x32_f16(wfrag[rt][kk], bf0, acc[rt][0], 0, 0, 0);
          acc[rt][1] = __builtin_amdgcn_mfma_f32_16x16x32_f16(wfrag[rt][kk], bf1, acc[rt][1], 0, 0, 0);
        }
      }
      #pragma unroll
      for (int rt = 0; rt < 4; ++rt)
        #pragma unroll
        for (int bt = 0; bt < 2; ++bt)
          #pragma unroll
          for (int p = 0; p < 4; ++p)
            part[wid][rt * 16 + hi * 4 + p][bt * 16 + lr] = acc[rt][bt][p];
    }
    __syncthreads();

    // ---- LSTM update: thread (ub, bb); h store is agent-coherent 2B ----
    {
      float g4[4];
      #pragma unroll
      for (int q = 0; q < 4; ++q) {
        int i = q * 16 + ub;
        float s = xg[q];
        #pragma unroll
        for (int w = 0; w < 8; ++w) s += part[w][i][bb];
        g4[q] = s;
      }
      float ig = 1.f / (1.f + __expf(-g4[0]));
      float fg = 1.f / (1.f + __expf(-g4[1]));
      float gg = tanhf(g4[2]);
      float og = 1.f / (1.f + __expf(-g4[3]));
      creg = fg * creg + ig * gg;
      float h = og * tanhf(creg);
      union { f16 h; unsigned short u; } cv;
      cv.h = (f16)h;
      __hip_atomic_store((unsigned short*)&HS[((size_t)bb * Tt + t) * HID + j0 + ub],
                         cv.u, __ATOMIC_RELAXED, __HIP_MEMORY_SCOPE_AGENT);
    }

    // ---- post completion flag (no fences: waitcnt + barrier order the stores) ----
    if (t != Tt - 1) {
      asm volatile("s_waitcnt vmcnt(0)" ::: "memory");  // my h stores are at IF
      __syncthreads();                                  // => all threads' are
      if (tid == 0)
        __hip_atomic_store(&bar[bid], (unsigned)(t + 1),
                           __ATOMIC_RELAXED, __HIP_MEMORY_SCOPE_AGENT);
    }
  }
}

extern "C" void kernel_launch(void* const* d_in, const int* in_sizes, int n_in,
                              void* d_out, int out_size, void* d_ws, size_t ws_size,
                              hipStream_t stream) {
  const float* z     = (const float*)d_in[0];
  const int*   x     = (const int*)d_in[1];
  const float* W_h   = (const float*)d_in[2];
  const float* b_h   = (const float*)d_in[3];
  const float* emb   = (const float*)d_in[4];
  const float* W_ih  = (const float*)d_in[5];
  const float* W_hh  = (const float*)d_in[6];
  const float* b_ih  = (const float*)d_in[7];
  const float* b_hh  = (const float*)d_in[8];
  const float* W_out = (const float*)d_in[9];
  const float* b_out = (const float*)d_in[10];
  float* out = (float*)d_out;

  char* ws = (char*)d_ws;
  size_t off = 0;
  auto carve = [&](size_t n) { char* p = ws + off; off += (n + 255) & ~(size_t)255; return p; };
  f16*   E16    = (f16*)carve((size_t)BT * DE * 2);     // 4 MB
  f16*   Wih16  = (f16*)carve((size_t)G4 * DE * 2);     // 4 MB
  f16*   Whh16  = (f16*)carve((size_t)G4 * HID * 2);    // 8 MB
  f16*   Wout16 = (f16*)carve((size_t)VOC * HID * 2);   // 64 MB
  float* XG2    = (float*)carve((size_t)BT * G4 * 4);   // 64 MB, [g][b][t]
  f16*   HS     = (f16*)carve((size_t)BT * HID * 2);    // 8 MB
  f16*   h0f    = (f16*)carve((size_t)Bb * HID * 2);
  float* bs     = (float*)carve((size_t)G4 * 4);
  unsigned* bar = (unsigned*)carve(256);

  (void)hipMemsetAsync(bar, 0, 256, stream);   // reset grid flags each call

  cvt_kernel<<<2048, 256, 0, stream>>>(W_ih,  Wih16,  G4 * DE / 4);
  cvt_kernel<<<2048, 256, 0, stream>>>(W_hh,  Whh16,  G4 * HID / 4);
  cvt_kernel<<<2048, 256, 0, stream>>>(W_out, Wout16, VOC * HID / 4);
  gather_kernel<<<BT * DE / 8 / 256, 256, 0, stream>>>(emb, x, E16);
  bsum_kernel<<<16, 256, 0, stream>>>(b_ih, b_hh, bs, G4);
  h0_kernel<<<128, 256, 0, stream>>>(z, W_h, b_h, h0f);

  dim3 g1(G4 / 128, BT / 128);     // 32 x 32
  gemm_kernel<true><<<g1, 256, 0, stream>>>(E16, Wih16, bs, XG2, BT, G4, DE);

  lstm_kernel<<<NB, 512, 0, stream>>>(Whh16, XG2, h0f, HS, bar);

  dim3 g2(VOC / 128, BT / 128);    // 250 x 32
  gemm_kernel<false><<<g2, 256, 0, stream>>>(HS, Wout16, b_out, out, BT, VOC, HID);
}